// Round 7
// baseline (86.287 us; speedup 1.0000x reference)
//
#include <hip/hip_runtime.h>
#include <math.h>

#define BB 128
#define CC 1024
#define SPLIT 32                 // blocks per batch
#define NBLK (BB * SPLIT)        // 4096
#define INV_N (1.0f / (float)(BB * CC))

// Fused kernel, counters zeroed by a leading memset node each call:
// triggers fire at the TRUE last arrival (old == K-1) -> exact on every call,
// no dependence on prior ws state. Visibility pattern (plain store ->
// __threadfence -> atomicAdd -> __threadfence -> plain loads) is the one R3
// empirically validated (absmax 0.0) on this chip; burst per counter address
// is capped at 32 RMWs by the 3-level hierarchy (32 -> 16 -> 8).
__global__ __launch_bounds__(64) void asl_fused_kernel(
    const float* __restrict__ x, const float* __restrict__ y,
    const float* __restrict__ mask,
    float* __restrict__ partial, float* __restrict__ bsum,
    float* __restrict__ gsum,
    unsigned int* __restrict__ cnt1, unsigned int* __restrict__ cnt2,
    unsigned int* __restrict__ cnt3, float* __restrict__ out) {
  const int blk   = blockIdx.x;
  const int b     = blk & (BB - 1);   // consecutive blocks: different batch
  const int chunk = blk >> 7;         // 0..31
  const int lane  = threadIdx.x;

  __shared__ unsigned short jidx[CC];
  __shared__ float          jw[CC];

  const float* xb = x + (size_t)b * CC;
  const float* yb = y + (size_t)b * CC;

  // Full row into registers for compaction.
  const float4* x4 = (const float4*)xb;
  const float4* y4 = (const float4*)yb;
  float4 xq[4], yq[4];
#pragma unroll
  for (int c = 0; c < 4; ++c) {
    xq[c] = x4[lane + 64 * c];
    yq[c] = y4[lane + 64 * c];
  }

  // ---- compaction: 16 ballots, deterministic order ----
  int base = 0;
#pragma unroll
  for (int c = 0; c < 4; ++c) {
    const float yv[4] = {yq[c].x, yq[c].y, yq[c].z, yq[c].w};
    const float xv[4] = {xq[c].x, xq[c].y, xq[c].z, xq[c].w};
#pragma unroll
    for (int q = 0; q < 4; ++q) {
      const bool p = (yv[q] != 0.0f);
      const unsigned long long bal = __ballot(p);
      if (p) {
        const int pos = base + __popcll(bal & ((1ull << lane) - 1ull));
        jidx[pos] = (unsigned short)(4 * (lane + 64 * c) + q);
        jw[pos]   = xv[q] * xv[q];
      }
      base += __popcll(bal);
    }
  }
  const int n = base;  // wave-uniform

  float acc = 0.0f;

  // ---- positives: entries dealt round-robin (e % SPLIT == chunk) ----
  for (int e = chunk; e < n; e += SPLIT) {
    const int ii = jidx[e];                        // uniform LDS broadcast
    const float* mrow = mask + (size_t)ii * CC;
    float mm = 0.0f;
    for (int k = lane; k < n; k += 64)
      mm = fmaxf(mm, mrow[jidx[k]] * jw[k]);       // mask 0/1; diag => mm>0
#pragma unroll
    for (int o = 32; o > 0; o >>= 1)
      mm = fmaxf(mm, __shfl_xor(mm, o, 64));
    if (lane == 0) acc += logf(mm);                // GAMMA_POS=0 -> log(xp)
  }

  // ---- negatives: chunks 0..15 cover i = chunk*64 + lane ----
  if (chunk < 16) {
    const int   i  = chunk * 64 + lane;
    const float xi = xb[i];
    const float yi = yb[i];
    if (yi == 0.0f) {
      const float x2 = xi * xi;
      acc += (x2 * x2) * logf(1.0f - xi);          // xp = x; xp^4*log(1-xp)
    }
  }

  // ---- wave reduce ----
#pragma unroll
  for (int o = 32; o > 0; o >>= 1)
    acc += __shfl_down(acc, o, 64);

  // ---- level 1: per-batch counter (exactly 32 increments, starts at 0) ----
  unsigned int old1 = 0;
  if (lane == 0) {
    partial[blk] = acc;                            // plain store
    __threadfence();                               // release (R3-proven)
    old1 = atomicAdd(&cnt1[b], 1u);                // device scope
  }
  old1 = (unsigned int)__shfl((int)old1, 0, 64);
  if (old1 != (unsigned)(SPLIT - 1)) return;

  // ---- batch reduce: 32 partials, fixed order (deterministic) ----
  __threadfence();                                 // acquire (R3-proven)
  float v1 = 0.0f;
  if (lane < SPLIT) v1 = partial[lane * BB + b];
#pragma unroll
  for (int o = 16; o > 0; o >>= 1)
    v1 += __shfl_xor(v1, o, 64);
  const int g = b >> 4;                            // 8 groups of 16 batches
  unsigned int old2 = 0;
  if (lane == 0) {
    bsum[b] = v1;
    __threadfence();
    old2 = atomicAdd(&cnt2[g], 1u);
  }
  old2 = (unsigned int)__shfl((int)old2, 0, 64);
  if (old2 != 15u) return;

  // ---- group reduce: 16 batch sums ----
  __threadfence();
  float v2 = 0.0f;
  if (lane < 16) v2 = bsum[g * 16 + lane];
#pragma unroll
  for (int o = 8; o > 0; o >>= 1)
    v2 += __shfl_xor(v2, o, 64);
  unsigned int old3 = 0;
  if (lane == 0) {
    gsum[g] = v2;
    __threadfence();
    old3 = atomicAdd(cnt3, 1u);
  }
  old3 = (unsigned int)__shfl((int)old3, 0, 64);
  if (old3 != 7u) return;

  // ---- final: 8 group sums -> out ----
  __threadfence();
  float v3 = 0.0f;
  if (lane < 8) v3 = gsum[lane];
#pragma unroll
  for (int o = 4; o > 0; o >>= 1)
    v3 += __shfl_xor(v3, o, 64);
  if (lane == 0) out[0] = -v3 * INV_N;
}

extern "C" void kernel_launch(void* const* d_in, const int* in_sizes, int n_in,
                              void* d_out, int out_size, void* d_ws, size_t ws_size,
                              hipStream_t stream) {
  const float* x    = (const float*)d_in[0];
  const float* y    = (const float*)d_in[1];
  const float* mask = (const float*)d_in[2];
  float* out = (float*)d_out;

  float* partial = (float*)d_ws;                   // 4096 floats
  float* bsum    = partial + NBLK;                 // 128 floats
  float* gsum    = bsum + BB;                      // 8 floats
  unsigned int* cnt1 = (unsigned int*)(gsum + 8);  // 128 uints
  unsigned int* cnt2 = cnt1 + BB;                  // 8 uints
  unsigned int* cnt3 = cnt2 + 8;                   // 1 uint

  // Zero the counter block every call (graph-capturable memset node).
  hipMemsetAsync((void*)cnt1, 0, (BB + 8 + 1) * sizeof(unsigned int), stream);

  asl_fused_kernel<<<NBLK, 64, 0, stream>>>(x, y, mask, partial, bsum, gsum,
                                            cnt1, cnt2, cnt3, out);
}

// Round 8
// 39.602 us; speedup vs baseline: 2.1788x; 2.1788x over previous
//
#include <hip/hip_runtime.h>
#include <math.h>

#define BB 128
#define CC 1024
#define SPLIT 16                 // blocks per batch
#define CHUNK (CC / SPLIT)       // 64 i's per block (one per lane)
#define NBLK (BB * SPLIT)        // 2048
#define INV_N (1.0f / (float)(BB * CC))

// Single compute kernel (R5 structure, proven exact) + ONE relaxed float
// atomicAdd per block into d_out (zeroed by a leading 4-byte memset node).
// No fences anywhere: atomic RMWs serialize at the coherence point on their
// own; no block ever READS another block's data. R3/R7 showed per-block
// __threadfence costs ~75us chip-wide -- this design has zero fences.
__global__ __launch_bounds__(64) void asl_main_kernel(
    const float* __restrict__ x, const float* __restrict__ y,
    const float* __restrict__ mask, float* __restrict__ out) {
  const int blk   = blockIdx.x;
  const int b     = blk & (BB - 1);   // consecutive blocks: different batch
  const int chunk = blk >> 7;         // 0..15
  const int lane  = threadIdx.x;

  __shared__ unsigned short jidx[CC];
  __shared__ float          jw[CC];

  const float* xb = x + (size_t)b * CC;
  const float* yb = y + (size_t)b * CC;

  // Full row into registers (for compaction).
  const float4* x4 = (const float4*)xb;
  const float4* y4 = (const float4*)yb;
  float4 xq[4], yq[4];
#pragma unroll
  for (int c = 0; c < 4; ++c) {
    xq[c] = x4[lane + 64 * c];
    yq[c] = y4[lane + 64 * c];
  }

  // Negative term inputs: one i per lane (scalar loads, cache-hot).
  const int   i  = chunk * CHUNK + lane;
  const float xi = xb[i];
  const float yi = yb[i];

  // ---- compaction: 16 ballots, deterministic order ----
  int base = 0;
#pragma unroll
  for (int c = 0; c < 4; ++c) {
    const float yv[4] = {yq[c].x, yq[c].y, yq[c].z, yq[c].w};
    const float xv[4] = {xq[c].x, xq[c].y, xq[c].z, xq[c].w};
#pragma unroll
    for (int q = 0; q < 4; ++q) {
      const bool p = (yv[q] != 0.0f);
      const unsigned long long bal = __ballot(p);
      if (p) {
        const int pos = base + __popcll(bal & ((1ull << lane) - 1ull));
        jidx[pos] = (unsigned short)(4 * (lane + 64 * c) + q);
        jw[pos]   = xv[q] * xv[q];
      }
      base += __popcll(bal);
    }
  }
  const int n = base;  // wave-uniform

  float acc = 0.0f;

  // ---- positives: entries e with e % SPLIT == chunk ----
  for (int e = chunk; e < n; e += SPLIT) {
    const int ii = jidx[e];                        // uniform LDS broadcast
    const float* mrow = mask + (size_t)ii * CC;
    float mm = 0.0f;
    for (int k = lane; k < n; k += 64)             // one round trip (n<=64 typ.)
      mm = fmaxf(mm, mrow[jidx[k]] * jw[k]);       // mask is 0/1; diag => mm>0
#pragma unroll
    for (int o = 32; o > 0; o >>= 1)
      mm = fmaxf(mm, __shfl_xor(mm, o, 64));
    if (lane == 0) acc += logf(mm);                // GAMMA_POS=0 -> log(xp)
  }

  // ---- negatives ----
  if (yi == 0.0f) {
    const float x2 = xi * xi;
    acc += (x2 * x2) * logf(1.0f - xi);            // xp = x; xp^4*log(1-xp)
  }

  // ---- wave reduce, one atomic per block ----
#pragma unroll
  for (int o = 32; o > 0; o >>= 1)
    acc += __shfl_down(acc, o, 64);
  if (lane == 0) atomicAdd(out, -acc * INV_N);     // no fence, no readers
}

extern "C" void kernel_launch(void* const* d_in, const int* in_sizes, int n_in,
                              void* d_out, int out_size, void* d_ws, size_t ws_size,
                              hipStream_t stream) {
  const float* x    = (const float*)d_in[0];
  const float* y    = (const float*)d_in[1];
  const float* mask = (const float*)d_in[2];
  float* out = (float*)d_out;

  // Zero the single output float each call (graph-capturable memset node).
  hipMemsetAsync((void*)out, 0, sizeof(float), stream);

  asl_main_kernel<<<NBLK, 64, 0, stream>>>(x, y, mask, out);
}

// Round 9
// 12.284 us; speedup vs baseline: 7.0243x; 3.2239x over previous
//
#include <hip/hip_runtime.h>
#include <math.h>

#define BB 128
#define CC 1024
#define SPLIT 32                 // blocks per batch
#define NBLK (BB * SPLIT)        // 4096
#define INV_N (1.0f / (float)(BB * CC))

// Two-node structure (structurally minimal: call #1 must be exact with
// arbitrary ws state, so any fused single-node reduction needs an init node
// anyway; and fences=75us / same-addr atomics=13ns*N are both worse than the
// ~3us second node). k1: 4096 single-wave blocks, <=2 gather rounds each.
__global__ __launch_bounds__(64) void asl_main_kernel(
    const float* __restrict__ x, const float* __restrict__ y,
    const float* __restrict__ mask, float* __restrict__ partial) {
  const int blk   = blockIdx.x;
  const int b     = blk & (BB - 1);   // consecutive blocks: different batch
  const int chunk = blk >> 7;         // 0..31
  const int lane  = threadIdx.x;

  __shared__ unsigned short jidx[CC];
  __shared__ float          jw[CC];

  const float* xb = x + (size_t)b * CC;
  const float* yb = y + (size_t)b * CC;

  // Full row into registers for compaction.
  const float4* x4 = (const float4*)xb;
  const float4* y4 = (const float4*)yb;
  float4 xq[4], yq[4];
#pragma unroll
  for (int c = 0; c < 4; ++c) {
    xq[c] = x4[lane + 64 * c];
    yq[c] = y4[lane + 64 * c];
  }

  // ---- compaction: 16 ballots, deterministic order ----
  int base = 0;
#pragma unroll
  for (int c = 0; c < 4; ++c) {
    const float yv[4] = {yq[c].x, yq[c].y, yq[c].z, yq[c].w};
    const float xv[4] = {xq[c].x, xq[c].y, xq[c].z, xq[c].w};
#pragma unroll
    for (int q = 0; q < 4; ++q) {
      const bool p = (yv[q] != 0.0f);
      const unsigned long long bal = __ballot(p);
      if (p) {
        const int pos = base + __popcll(bal & ((1ull << lane) - 1ull));
        jidx[pos] = (unsigned short)(4 * (lane + 64 * c) + q);
        jw[pos]   = xv[q] * xv[q];
      }
      base += __popcll(bal);
    }
  }
  const int n = base;  // wave-uniform

  float acc = 0.0f;

  // ---- positives: entries dealt round-robin (e % SPLIT == chunk) ----
  for (int e = chunk; e < n; e += SPLIT) {
    const int ii = jidx[e];                        // uniform LDS broadcast
    const float* mrow = mask + (size_t)ii * CC;
    float mm = 0.0f;
    for (int k = lane; k < n; k += 64)
      mm = fmaxf(mm, mrow[jidx[k]] * jw[k]);       // mask 0/1; diag => mm>0
#pragma unroll
    for (int o = 32; o > 0; o >>= 1)
      mm = fmaxf(mm, __shfl_xor(mm, o, 64));
    if (lane == 0) acc += logf(mm);                // GAMMA_POS=0 -> log(xp)
  }

  // ---- negatives: chunks 0..15 cover i = chunk*64 + lane ----
  if (chunk < 16) {
    const int   i  = chunk * 64 + lane;
    const float xi = xb[i];
    const float yi = yb[i];
    if (yi == 0.0f) {
      const float x2 = xi * xi;
      acc += (x2 * x2) * logf(1.0f - xi);          // xp = x; xp^4*log(1-xp)
    }
  }

  // ---- wave reduce, publish ----
#pragma unroll
  for (int o = 32; o > 0; o >>= 1)
    acc += __shfl_down(acc, o, 64);
  if (lane == 0) partial[blk] = acc;
}

// Deterministic NBLK -> 1 reduction, negated mean. float4 loads.
__global__ __launch_bounds__(256) void asl_final_kernel(
    const float* __restrict__ partial, float* __restrict__ out) {
  const int tid = threadIdx.x;
  const float4* p4 = (const float4*)partial;
  float v = 0.0f;
#pragma unroll
  for (int r = 0; r < NBLK / 4 / 256; ++r) {
    const float4 q = p4[tid + 256 * r];
    v += (q.x + q.y) + (q.z + q.w);
  }
#pragma unroll
  for (int o = 32; o > 0; o >>= 1)
    v += __shfl_down(v, o, 64);
  __shared__ float s[4];
  if ((tid & 63) == 0) s[tid >> 6] = v;
  __syncthreads();
  if (tid == 0) out[0] = -(s[0] + s[1] + s[2] + s[3]) * INV_N;
}

extern "C" void kernel_launch(void* const* d_in, const int* in_sizes, int n_in,
                              void* d_out, int out_size, void* d_ws, size_t ws_size,
                              hipStream_t stream) {
  const float* x    = (const float*)d_in[0];
  const float* y    = (const float*)d_in[1];
  const float* mask = (const float*)d_in[2];
  float* out     = (float*)d_out;
  float* partial = (float*)d_ws;   // NBLK floats, fully rewritten each call

  asl_main_kernel<<<NBLK, 64, 0, stream>>>(x, y, mask, partial);
  asl_final_kernel<<<1, 256, 0, stream>>>(partial, out);
}